// Round 1
// baseline (1198.178 us; speedup 1.0000x reference)
//
#include <hip/hip_runtime.h>
#include <cstdint>
#include <cstddef>

#define NB 128
#define NT 512
#define NJ 21
#define NC 3
#define NH 64
#define JH 1344   // NJ*NH
#define G3 192    // 3*NH
#define OUT0 (NB*NJ*NC) // 8064

__device__ __forceinline__ float bf2f(unsigned short u) {
  union { unsigned int i; float f; } v; v.i = ((unsigned int)u) << 16; return v.f;
}
__device__ __forceinline__ unsigned short f2bf(float f) {
  union { float f; unsigned int i; } v; v.f = f;
  unsigned int x = v.i;
  unsigned int lsb = (x >> 16) & 1u;
  x += 0x7fffu + lsb;
  return (unsigned short)(x >> 16);
}

// ---------------- K1: GCN x2 per (b,t) frame + score partials + h2(bf16) store
// grid (NB, 16), block 256. Each wave handles 8 consecutive t of one batch.
__global__ __launch_bounds__(256) void k1_gcn(
    const float* __restrict__ x, const float* __restrict__ A,
    const float* __restrict__ W1, const float* __restrict__ b1,
    const float* __restrict__ W2, const float* __restrict__ b2,
    const float* __restrict__ Wa,
    unsigned short* __restrict__ h2out, float* __restrict__ scorepart) {
  __shared__ float A_s[NJ*NJ];
  __shared__ float xs[4][64];
  __shared__ float aggs[4][64];
  __shared__ float a2s[4][JH];
  __shared__ float red[4][NJ];
  const int tid = threadIdx.x;
  const int w = tid >> 6, lane = tid & 63;
  const int b = blockIdx.x, ch = blockIdx.y;

  for (int i = tid; i < NJ*NJ; i += 256) A_s[i] = A[i];
  const float w1r0 = W1[lane*3+0], w1r1 = W1[lane*3+1], w1r2 = W1[lane*3+2];
  const float b1h = b1[lane], b2h = b2[lane], wah = Wa[lane];
  float w2r[64];
  {
    const float4* p = (const float4*)(W2 + lane*64);
#pragma unroll
    for (int q = 0; q < 16; ++q) {
      float4 v = p[q];
      w2r[4*q+0]=v.x; w2r[4*q+1]=v.y; w2r[4*q+2]=v.z; w2r[4*q+3]=v.w;
    }
  }
  float spart[NJ];
#pragma unroll
  for (int i = 0; i < NJ; ++i) spart[i] = 0.f;
  __syncthreads();

  for (int tt = 0; tt < 8; ++tt) {
    const int t = ch*32 + w*8 + tt;
    if (lane < NJ*NC) xs[w][lane] = x[(size_t)(b*NT + t)*(NJ*NC) + lane];
    __syncthreads();
    if (lane < NJ*NC) {
      const int i = lane / 3, c = lane % 3;
      float s = 0.f;
#pragma unroll
      for (int j = 0; j < NJ; ++j) s += A_s[i*NJ + j] * xs[w][j*3 + c];
      aggs[w][lane] = s;
    }
    __syncthreads();
    // h1 (layer 1 linear + relu); lane = h channel
    float h1r[NJ];
#pragma unroll
    for (int j = 0; j < NJ; ++j) {
      float s = b1h + w1r0*aggs[w][j*3+0] + w1r1*aggs[w][j*3+1] + w1r2*aggs[w][j*3+2];
      h1r[j] = fmaxf(s, 0.f);
    }
    // agg2 = A @ h1  -> stage to LDS for cross-lane GEMM
    for (int i = 0; i < NJ; ++i) {
      float s = 0.f;
#pragma unroll
      for (int j = 0; j < NJ; ++j) s += A_s[i*NJ + j] * h1r[j];
      a2s[w][i*64 + lane] = s;
    }
    __syncthreads();
    // h2 = relu(agg2 @ W2.T + b2); lane = h
    unsigned short* hrow = h2out + (size_t)(b*NT + t)*JH;
    const float4* a2v = (const float4*)(&a2s[w][0]);
#pragma unroll
    for (int i = 0; i < NJ; ++i) {
      float s = b2h;
#pragma unroll
      for (int q = 0; q < 16; ++q) {
        float4 v = a2v[i*16 + q];  // broadcast read, conflict-free
        s += v.x*w2r[4*q+0] + v.y*w2r[4*q+1] + v.z*w2r[4*q+2] + v.w*w2r[4*q+3];
      }
      s = fmaxf(s, 0.f);
      spart[i] += s * wah;
      hrow[i*64 + lane] = f2bf(s);
    }
    __syncthreads();
  }

  // deterministic cross-lane + cross-wave score reduction
#pragma unroll
  for (int i = 0; i < NJ; ++i) {
    float r = spart[i];
    r += __shfl_xor(r, 32); r += __shfl_xor(r, 16); r += __shfl_xor(r, 8);
    r += __shfl_xor(r, 4);  r += __shfl_xor(r, 2);  r += __shfl_xor(r, 1);
    if (lane == 0) red[w][i] = r;
  }
  __syncthreads();
  if (tid < NJ) {
    float s = red[0][tid] + red[1][tid] + red[2][tid] + red[3][tid];
    scorepart[(b*16 + ch)*NJ + tid] = s;
  }
}

// ---------------- K2: reduce score partials, softmax over joints
__global__ __launch_bounds__(64) void k2_attn(
    const float* __restrict__ scorepart, float* __restrict__ attn,
    float* __restrict__ out_attn) {
  __shared__ float ss[NJ];
  const int b = blockIdx.x, tid = threadIdx.x;
  if (tid < NJ) {
    float s = 0.f;
    for (int ch = 0; ch < 16; ++ch) s += scorepart[(b*16 + ch)*NJ + tid];
    ss[tid] = s * (1.0f/NT);   // + ba dropped: softmax-invariant
  }
  __syncthreads();
  float m = -1e30f;
  for (int j = 0; j < NJ; ++j) m = fmaxf(m, ss[j]);
  float sum = 0.f;
  for (int j = 0; j < NJ; ++j) sum += expf(ss[j] - m);
  if (tid < NJ) {
    float a = expf(ss[tid] - m) / sum;
    attn[b*NJ + tid] = a;
    out_attn[b*NJ + tid] = a;
  }
}

// ---------------- K3: xproj = (h2 * attn) @ W_ih.T + b_ih
// grid (16, NB), block 256; tile 32t x 192g, k-chunks of 32
__global__ __launch_bounds__(256) void k3_xproj(
    const unsigned short* __restrict__ h2, const float* __restrict__ W_ih,
    const float* __restrict__ b_ih, const float* __restrict__ attn,
    float* __restrict__ xproj) {
  __shared__ float As[32][32];     // [t][k], reads are broadcast
  __shared__ float Ws[32][201];    // transposed W chunk [k][g], padded stride
  const int tid = threadIdx.x;
  const int b = blockIdx.y;
  const int t0 = blockIdx.x * 32;
  const int tg = tid & 31, tr = tid >> 5;   // thread tile: 4 t x 6 g
  float acc[4][6];
#pragma unroll
  for (int i = 0; i < 4; ++i)
#pragma unroll
    for (int u = 0; u < 6; ++u) acc[i][u] = 0.f;

  for (int kc = 0; kc < 42; ++kc) {
    const int k0 = kc * 32;
    const float scale = attn[b*NJ + (k0 >> 6)];  // one joint per 32-chunk
    {
      const int row = tid >> 3, c4 = tid & 7;
      const unsigned short* p = h2 + (size_t)(b*NT + t0 + row)*JH + k0 + c4*4;
      const uint2 u = *(const uint2*)p;
      As[row][c4*4+0] = scale * bf2f((unsigned short)(u.x & 0xffff));
      As[row][c4*4+1] = scale * bf2f((unsigned short)(u.x >> 16));
      As[row][c4*4+2] = scale * bf2f((unsigned short)(u.y & 0xffff));
      As[row][c4*4+3] = scale * bf2f((unsigned short)(u.y >> 16));
    }
#pragma unroll
    for (int l = 0; l < 6; ++l) {
      const int idx = l*256 + tid;
      const int g = idx >> 3, c4 = idx & 7;
      const float4 v = *(const float4*)(W_ih + (size_t)g*JH + k0 + c4*4);
      Ws[c4*4+0][g] = v.x; Ws[c4*4+1][g] = v.y;
      Ws[c4*4+2][g] = v.z; Ws[c4*4+3][g] = v.w;
    }
    __syncthreads();
#pragma unroll 4
    for (int k = 0; k < 32; ++k) {
      float a0 = As[tr*4+0][k], a1 = As[tr*4+1][k];
      float a2 = As[tr*4+2][k], a3 = As[tr*4+3][k];
      float w0 = Ws[k][tg*6+0], w1 = Ws[k][tg*6+1], w2 = Ws[k][tg*6+2];
      float w3 = Ws[k][tg*6+3], w4 = Ws[k][tg*6+4], w5 = Ws[k][tg*6+5];
      acc[0][0] += a0*w0; acc[0][1] += a0*w1; acc[0][2] += a0*w2;
      acc[0][3] += a0*w3; acc[0][4] += a0*w4; acc[0][5] += a0*w5;
      acc[1][0] += a1*w0; acc[1][1] += a1*w1; acc[1][2] += a1*w2;
      acc[1][3] += a1*w3; acc[1][4] += a1*w4; acc[1][5] += a1*w5;
      acc[2][0] += a2*w0; acc[2][1] += a2*w1; acc[2][2] += a2*w2;
      acc[2][3] += a2*w3; acc[2][4] += a2*w4; acc[2][5] += a2*w5;
      acc[3][0] += a3*w0; acc[3][1] += a3*w1; acc[3][2] += a3*w2;
      acc[3][3] += a3*w3; acc[3][4] += a3*w4; acc[3][5] += a3*w5;
    }
    __syncthreads();
  }
#pragma unroll
  for (int i = 0; i < 4; ++i) {
    const int t = t0 + tr*4 + i;
#pragma unroll
    for (int u = 0; u < 6; ++u) {
      const int g = tg*6 + u;
      xproj[(size_t)(b*NT + t)*G3 + g] = acc[i][u] + b_ih[g];
    }
  }
}

// ---------------- K4: GRU over time, one block per batch
__global__ __launch_bounds__(192) void k4_gru(
    const float* __restrict__ xproj, const float* __restrict__ W_hh,
    const float* __restrict__ b_hh, float* __restrict__ hT) {
  __shared__ float h_s[2][NH];
  __shared__ float rz_s[2*NH];
  __shared__ float xn_s[NH];
  __shared__ float hn_s[NH];
  const int b = blockIdx.x, g = threadIdx.x;
  float wh[NH];
  {
    const float4* p = (const float4*)(W_hh + g*NH);
#pragma unroll
    for (int q = 0; q < 16; ++q) {
      float4 v = p[q];
      wh[4*q+0]=v.x; wh[4*q+1]=v.y; wh[4*q+2]=v.z; wh[4*q+3]=v.w;
    }
  }
  const float bh = b_hh[g];
  if (g < NH) h_s[0][g] = 0.f;
  __syncthreads();
  int cur = 0;
  const float* xp_base = xproj + (size_t)b*NT*G3;
  float xp = xp_base[g];   // t=0 prefetch
  for (int t = 0; t < NT; ++t) {
    float xp_next = (t+1 < NT) ? xp_base[(size_t)(t+1)*G3 + g] : 0.f;
    float a0=0.f, a1=0.f, a2=0.f, a3=0.f;
    const float4* h4 = (const float4*)(h_s[cur]);
#pragma unroll
    for (int q = 0; q < 16; q += 4) {
      float4 v0 = h4[q+0], v1 = h4[q+1], v2 = h4[q+2], v3 = h4[q+3];
      a0 += v0.x*wh[4*q+0]  + v0.y*wh[4*q+1]  + v0.z*wh[4*q+2]  + v0.w*wh[4*q+3];
      a1 += v1.x*wh[4*q+4]  + v1.y*wh[4*q+5]  + v1.z*wh[4*q+6]  + v1.w*wh[4*q+7];
      a2 += v2.x*wh[4*q+8]  + v2.y*wh[4*q+9]  + v2.z*wh[4*q+10] + v2.w*wh[4*q+11];
      a3 += v3.x*wh[4*q+12] + v3.y*wh[4*q+13] + v3.z*wh[4*q+14] + v3.w*wh[4*q+15];
    }
    const float gh = bh + ((a0 + a1) + (a2 + a3));
    if (g < 2*NH) { rz_s[g] = xp + gh; }
    else          { xn_s[g-2*NH] = xp; hn_s[g-2*NH] = gh; }
    __syncthreads();
    if (g < NH) {
      const float r = 1.f/(1.f + expf(-rz_s[g]));
      const float z = 1.f/(1.f + expf(-rz_s[NH+g]));
      const float n = tanhf(xn_s[g] + r*hn_s[g]);
      h_s[cur^1][g] = (1.f - z)*n + z*h_s[cur][g];
    }
    __syncthreads();
    cur ^= 1;
    xp = xp_next;
  }
  if (g < NH) hT[b*NH + g] = h_s[cur][g];
}

// ---------------- K5: head
__global__ __launch_bounds__(256) void k5_head(
    const float* __restrict__ hT, const float* __restrict__ W_head,
    const float* __restrict__ b_head, float* __restrict__ out) {
  const int idx = blockIdx.x*256 + threadIdx.x;
  if (idx >= NB*63) return;
  const int b = idx / 63, r = idx % 63;
  const float* hv = hT + b*NH;
  const float* wr = W_head + r*NH;
  float acc = b_head[r];
#pragma unroll
  for (int k = 0; k < NH; ++k) acc += hv[k]*wr[k];
  out[idx] = acc;
}

extern "C" void kernel_launch(void* const* d_in, const int* in_sizes, int n_in,
                              void* d_out, int out_size, void* d_ws, size_t ws_size,
                              hipStream_t stream) {
  const float* x      = (const float*)d_in[0];
  const float* A      = (const float*)d_in[1];
  const float* W1     = (const float*)d_in[2];
  const float* b1     = (const float*)d_in[3];
  const float* W2     = (const float*)d_in[4];
  const float* b2     = (const float*)d_in[5];
  const float* Wa     = (const float*)d_in[6];
  // d_in[7] = ba : softmax-invariant, unused
  const float* W_ih   = (const float*)d_in[8];
  const float* b_ih   = (const float*)d_in[9];
  const float* W_hh   = (const float*)d_in[10];
  const float* b_hh   = (const float*)d_in[11];
  const float* W_head = (const float*)d_in[12];
  const float* b_head = (const float*)d_in[13];
  float* out = (float*)d_out;

  char* ws = (char*)d_ws;
  size_t off = 0;
  unsigned short* h2 = (unsigned short*)(ws + off); off += (size_t)NB*NT*JH*2;  // 176 MB
  float* scorepart   = (float*)(ws + off);          off += (size_t)NB*16*NJ*4;
  float* attn        = (float*)(ws + off);          off += (size_t)NB*NJ*4;
  // align to 16B
  off = (off + 15) & ~(size_t)15;
  float* xproj       = (float*)(ws + off);          off += (size_t)NB*NT*G3*4;  // 50 MB
  float* hT          = (float*)(ws + off);          off += (size_t)NB*NH*4;

  k1_gcn <<<dim3(NB, 16), 256, 0, stream>>>(x, A, W1, b1, W2, b2, Wa, h2, scorepart);
  k2_attn<<<dim3(NB),      64, 0, stream>>>(scorepart, attn, out + OUT0);
  k3_xproj<<<dim3(16, NB), 256, 0, stream>>>(h2, W_ih, b_ih, attn, xproj);
  k4_gru <<<dim3(NB),     192, 0, stream>>>(xproj, W_hh, b_hh, hT);
  k5_head<<<dim3((NB*63 + 255)/256), 256, 0, stream>>>(hT, W_head, b_head, out);
}

// Round 2
// 758.814 us; speedup vs baseline: 1.5790x; 1.5790x over previous
//
#include <hip/hip_runtime.h>
#include <cstdint>
#include <cstddef>

#define NB 128
#define NT 512
#define NJ 21
#define NC 3
#define NH 64
#define JH 1344   // NJ*NH
#define G3 192    // 3*NH
#define OUT0 (NB*NJ*NC) // 8064

typedef __attribute__((ext_vector_type(8))) __bf16 bf16x8;
typedef __attribute__((ext_vector_type(4))) float f32x4;

__device__ __forceinline__ float bf2f(unsigned short u) {
  union { unsigned int i; float f; } v; v.i = ((unsigned int)u) << 16; return v.f;
}
__device__ __forceinline__ unsigned short f2bf(float f) {
  union { float f; unsigned int i; } v; v.f = f;
  unsigned int x = v.i;
  unsigned int lsb = (x >> 16) & 1u;
  x += 0x7fffu + lsb;
  return (unsigned short)(x >> 16);
}
__device__ __forceinline__ unsigned int pk_bf16(float lo, float hi) {
  unsigned int r;
  asm("v_cvt_pk_bf16_f32 %0, %1, %2" : "=v"(r) : "v"(lo), "v"(hi));
  return r;
}
// scale two packed bf16 by s, repack (RNE)
__device__ __forceinline__ unsigned int scale2(unsigned int u, float s) {
  float lo = __uint_as_float(u << 16);
  float hi = __uint_as_float(u & 0xffff0000u);
  return pk_bf16(lo * s, hi * s);
}

// ---------------- K0: convert W_ih (192x1344 f32) to bf16
__global__ __launch_bounds__(256) void k0_convw(
    const float* __restrict__ W, unsigned short* __restrict__ Wbf) {
  const int ti = blockIdx.x*256 + threadIdx.x;   // 64512 threads, 4 elems each
  const float4 v = ((const float4*)W)[ti];
  uint2 o;
  o.x = (unsigned int)f2bf(v.x) | ((unsigned int)f2bf(v.y) << 16);
  o.y = (unsigned int)f2bf(v.z) | ((unsigned int)f2bf(v.w) << 16);
  ((uint2*)Wbf)[ti] = o;
}

// ---------------- K1: GCN x2 per (b,t) frame + score partials + h2(bf16) store
__global__ __launch_bounds__(256) void k1_gcn(
    const float* __restrict__ x, const float* __restrict__ A,
    const float* __restrict__ W1, const float* __restrict__ b1,
    const float* __restrict__ W2, const float* __restrict__ b2,
    const float* __restrict__ Wa,
    unsigned short* __restrict__ h2out, float* __restrict__ scorepart) {
  __shared__ float A_s[NJ*NJ];
  __shared__ float xs[4][64];
  __shared__ float aggs[4][64];
  __shared__ float a2s[4][JH];
  __shared__ float red[4][NJ];
  const int tid = threadIdx.x;
  const int w = tid >> 6, lane = tid & 63;
  const int b = blockIdx.x, ch = blockIdx.y;

  for (int i = tid; i < NJ*NJ; i += 256) A_s[i] = A[i];
  const float w1r0 = W1[lane*3+0], w1r1 = W1[lane*3+1], w1r2 = W1[lane*3+2];
  const float b1h = b1[lane], b2h = b2[lane], wah = Wa[lane];
  float w2r[64];
  {
    const float4* p = (const float4*)(W2 + lane*64);
#pragma unroll
    for (int q = 0; q < 16; ++q) {
      float4 v = p[q];
      w2r[4*q+0]=v.x; w2r[4*q+1]=v.y; w2r[4*q+2]=v.z; w2r[4*q+3]=v.w;
    }
  }
  float spart[NJ];
#pragma unroll
  for (int i = 0; i < NJ; ++i) spart[i] = 0.f;
  __syncthreads();

  for (int tt = 0; tt < 8; ++tt) {
    const int t = ch*32 + w*8 + tt;
    if (lane < NJ*NC) xs[w][lane] = x[(size_t)(b*NT + t)*(NJ*NC) + lane];
    __syncthreads();
    if (lane < NJ*NC) {
      const int i = lane / 3, c = lane % 3;
      float s = 0.f;
#pragma unroll
      for (int j = 0; j < NJ; ++j) s += A_s[i*NJ + j] * xs[w][j*3 + c];
      aggs[w][lane] = s;
    }
    __syncthreads();
    float h1r[NJ];
#pragma unroll
    for (int j = 0; j < NJ; ++j) {
      float s = b1h + w1r0*aggs[w][j*3+0] + w1r1*aggs[w][j*3+1] + w1r2*aggs[w][j*3+2];
      h1r[j] = fmaxf(s, 0.f);
    }
    for (int i = 0; i < NJ; ++i) {
      float s = 0.f;
#pragma unroll
      for (int j = 0; j < NJ; ++j) s += A_s[i*NJ + j] * h1r[j];
      a2s[w][i*64 + lane] = s;
    }
    __syncthreads();
    unsigned short* hrow = h2out + (size_t)(b*NT + t)*JH;
    const float4* a2v = (const float4*)(&a2s[w][0]);
#pragma unroll
    for (int i = 0; i < NJ; ++i) {
      float s = b2h;
#pragma unroll
      for (int q = 0; q < 16; ++q) {
        float4 v = a2v[i*16 + q];
        s += v.x*w2r[4*q+0] + v.y*w2r[4*q+1] + v.z*w2r[4*q+2] + v.w*w2r[4*q+3];
      }
      s = fmaxf(s, 0.f);
      spart[i] += s * wah;
      hrow[i*64 + lane] = f2bf(s);
    }
    __syncthreads();
  }

#pragma unroll
  for (int i = 0; i < NJ; ++i) {
    float r = spart[i];
    r += __shfl_xor(r, 32); r += __shfl_xor(r, 16); r += __shfl_xor(r, 8);
    r += __shfl_xor(r, 4);  r += __shfl_xor(r, 2);  r += __shfl_xor(r, 1);
    if (lane == 0) red[w][i] = r;
  }
  __syncthreads();
  if (tid < NJ) {
    float s = red[0][tid] + red[1][tid] + red[2][tid] + red[3][tid];
    scorepart[(b*16 + ch)*NJ + tid] = s;
  }
}

// ---------------- K2: reduce score partials, softmax over joints
__global__ __launch_bounds__(64) void k2_attn(
    const float* __restrict__ scorepart, float* __restrict__ attn,
    float* __restrict__ out_attn) {
  __shared__ float ss[NJ];
  const int b = blockIdx.x, tid = threadIdx.x;
  if (tid < NJ) {
    float s = 0.f;
    for (int ch = 0; ch < 16; ++ch) s += scorepart[(b*16 + ch)*NJ + tid];
    ss[tid] = s * (1.0f/NT);
  }
  __syncthreads();
  float m = -1e30f;
  for (int j = 0; j < NJ; ++j) m = fmaxf(m, ss[j]);
  float sum = 0.f;
  for (int j = 0; j < NJ; ++j) sum += expf(ss[j] - m);
  if (tid < NJ) {
    float a = expf(ss[tid] - m) / sum;
    attn[b*NJ + tid] = a;
    out_attn[b*NJ + tid] = a;
  }
}

// ---------------- K3: xproj = (h2 * attn) @ W_ih.T + b_ih  -- MFMA bf16
// Grid 512 blocks: block = (b, 128-row m-tile) x full N=192. 4 waves 2Mx2N,
// wave tile 64x96. BK=32, double-buffered LDS, XOR chunk swizzle (2-way = free).
// attn scale folded into B staging (uniform scalar per k-step since 32|64).
__global__ __launch_bounds__(256, 2) void k3_xproj_mfma(
    const unsigned short* __restrict__ h2, const unsigned short* __restrict__ Wbf,
    const float* __restrict__ b_ih, const float* __restrict__ attn,
    float* __restrict__ xproj) {
  __shared__ unsigned short Abuf[2][128*32];   // 2 x 8 KB
  __shared__ unsigned short Bbuf[2][192*32];   // 2 x 12 KB
  const int tid = threadIdx.x;
  const int w = tid >> 6, l = tid & 63;
  const int lq = l >> 4, lr = l & 15;
  const int blk = blockIdx.x;
  const int b = blk >> 2;
  const int t0 = (blk & 3) << 7;
  const int wm = w >> 1, wn = w & 1;

  // staging address precompute (k-step adds kk to global, LDS offsets fixed)
  const unsigned short* gA[2]; int ldsA[2];
#pragma unroll
  for (int i = 0; i < 2; ++i) {
    const int lc = tid*2 + i, r = lc >> 2, j = lc & 3;
    gA[i] = h2 + (size_t)(b*NT + t0 + r)*JH + j*8;
    ldsA[i] = r*32 + ((j ^ ((r>>1)&3)) << 3);
  }
  const unsigned short* gB[3]; int ldsB[3];
#pragma unroll
  for (int i = 0; i < 3; ++i) {
    const int lc = tid + 256*i, g = lc >> 2, j = lc & 3;
    gB[i] = Wbf + (size_t)g*JH + j*8;
    ldsB[i] = g*32 + ((j ^ ((g>>1)&3)) << 3);
  }
  // fragment LDS offsets (k-step invariant)
  int aoff[4], boff[6];
#pragma unroll
  for (int mt = 0; mt < 4; ++mt) {
    const int row = wm*64 + mt*16 + lr;
    aoff[mt] = row*32 + ((lq ^ ((row>>1)&3)) << 3);
  }
#pragma unroll
  for (int nt = 0; nt < 6; ++nt) {
    const int g = wn*96 + nt*16 + lr;
    boff[nt] = g*32 + ((lq ^ ((g>>1)&3)) << 3);
  }

  f32x4 acc[4][6];
#pragma unroll
  for (int mt = 0; mt < 4; ++mt)
#pragma unroll
    for (int nt = 0; nt < 6; ++nt) acc[mt][nt] = (f32x4)0.f;

  // prologue: stage ks=0 into buf 0
  {
    const float s = attn[b*NJ + 0];
#pragma unroll
    for (int i = 0; i < 2; ++i)
      *(uint4*)(&Abuf[0][ldsA[i]]) = *(const uint4*)(gA[i]);
#pragma unroll
    for (int i = 0; i < 3; ++i) {
      uint4 v = *(const uint4*)(gB[i]);
      v.x = scale2(v.x, s); v.y = scale2(v.y, s);
      v.z = scale2(v.z, s); v.w = scale2(v.w, s);
      *(uint4*)(&Bbuf[0][ldsB[i]]) = v;
    }
  }
  __syncthreads();

  for (int ks = 0; ks < 42; ++ks) {
    const int cur = ks & 1;
    uint4 av0, av1, bv0, bv1, bv2;
    if (ks < 41) {
      const int kk = (ks+1)*32;
      av0 = *(const uint4*)(gA[0] + kk);
      av1 = *(const uint4*)(gA[1] + kk);
      bv0 = *(const uint4*)(gB[0] + kk);
      bv1 = *(const uint4*)(gB[1] + kk);
      bv2 = *(const uint4*)(gB[2] + kk);
    }
    bf16x8 af[4], bfr[6];
#pragma unroll
    for (int mt = 0; mt < 4; ++mt) af[mt] = *(const bf16x8*)(&Abuf[cur][aoff[mt]]);
#pragma unroll
    for (int nt = 0; nt < 6; ++nt) bfr[nt] = *(const bf16x8*)(&Bbuf[cur][boff[nt]]);
#pragma unroll
    for (int mt = 0; mt < 4; ++mt)
#pragma unroll
      for (int nt = 0; nt < 6; ++nt)
        acc[mt][nt] = __builtin_amdgcn_mfma_f32_16x16x32_bf16(af[mt], bfr[nt], acc[mt][nt], 0, 0, 0);
    if (ks < 41) {
      const float s = attn[b*NJ + ((ks+1) >> 1)];
      *(uint4*)(&Abuf[cur^1][ldsA[0]]) = av0;
      *(uint4*)(&Abuf[cur^1][ldsA[1]]) = av1;
      uint4 v;
      v = bv0; v.x = scale2(v.x, s); v.y = scale2(v.y, s); v.z = scale2(v.z, s); v.w = scale2(v.w, s);
      *(uint4*)(&Bbuf[cur^1][ldsB[0]]) = v;
      v = bv1; v.x = scale2(v.x, s); v.y = scale2(v.y, s); v.z = scale2(v.z, s); v.w = scale2(v.w, s);
      *(uint4*)(&Bbuf[cur^1][ldsB[1]]) = v;
      v = bv2; v.x = scale2(v.x, s); v.y = scale2(v.y, s); v.z = scale2(v.z, s); v.w = scale2(v.w, s);
      *(uint4*)(&Bbuf[cur^1][ldsB[2]]) = v;
    }
    __syncthreads();
  }

  // epilogue: bias + store
  float bias[6];
#pragma unroll
  for (int nt = 0; nt < 6; ++nt) bias[nt] = b_ih[wn*96 + nt*16 + lr];
#pragma unroll
  for (int mt = 0; mt < 4; ++mt)
#pragma unroll
    for (int nt = 0; nt < 6; ++nt) {
      const int g = wn*96 + nt*16 + lr;
#pragma unroll
      for (int r = 0; r < 4; ++r) {
        const int trow = t0 + wm*64 + mt*16 + lq*4 + r;
        xproj[(size_t)(b*NT + trow)*G3 + g] = acc[mt][nt][r] + bias[nt];
      }
    }
}

// ---------------- K4: GRU over time, one block per batch
__global__ __launch_bounds__(192) void k4_gru(
    const float* __restrict__ xproj, const float* __restrict__ W_hh,
    const float* __restrict__ b_hh, float* __restrict__ hT) {
  __shared__ float h_s[2][NH];
  __shared__ float rz_s[2*NH];
  __shared__ float xn_s[NH];
  __shared__ float hn_s[NH];
  const int b = blockIdx.x, g = threadIdx.x;
  float wh[NH];
  {
    const float4* p = (const float4*)(W_hh + g*NH);
#pragma unroll
    for (int q = 0; q < 16; ++q) {
      float4 v = p[q];
      wh[4*q+0]=v.x; wh[4*q+1]=v.y; wh[4*q+2]=v.z; wh[4*q+3]=v.w;
    }
  }
  const float bh = b_hh[g];
  if (g < NH) h_s[0][g] = 0.f;
  __syncthreads();
  int cur = 0;
  const float* xp_base = xproj + (size_t)b*NT*G3;
  float xp = xp_base[g];
  for (int t = 0; t < NT; ++t) {
    float xp_next = (t+1 < NT) ? xp_base[(size_t)(t+1)*G3 + g] : 0.f;
    float a0=0.f, a1=0.f, a2=0.f, a3=0.f;
    const float4* h4 = (const float4*)(h_s[cur]);
#pragma unroll
    for (int q = 0; q < 16; q += 4) {
      float4 v0 = h4[q+0], v1 = h4[q+1], v2 = h4[q+2], v3 = h4[q+3];
      a0 += v0.x*wh[4*q+0]  + v0.y*wh[4*q+1]  + v0.z*wh[4*q+2]  + v0.w*wh[4*q+3];
      a1 += v1.x*wh[4*q+4]  + v1.y*wh[4*q+5]  + v1.z*wh[4*q+6]  + v1.w*wh[4*q+7];
      a2 += v2.x*wh[4*q+8]  + v2.y*wh[4*q+9]  + v2.z*wh[4*q+10] + v2.w*wh[4*q+11];
      a3 += v3.x*wh[4*q+12] + v3.y*wh[4*q+13] + v3.z*wh[4*q+14] + v3.w*wh[4*q+15];
    }
    const float gh = bh + ((a0 + a1) + (a2 + a3));
    if (g < 2*NH) { rz_s[g] = xp + gh; }
    else          { xn_s[g-2*NH] = xp; hn_s[g-2*NH] = gh; }
    __syncthreads();
    if (g < NH) {
      const float r = 1.f/(1.f + expf(-rz_s[g]));
      const float z = 1.f/(1.f + expf(-rz_s[NH+g]));
      const float n = tanhf(xn_s[g] + r*hn_s[g]);
      h_s[cur^1][g] = (1.f - z)*n + z*h_s[cur][g];
    }
    __syncthreads();
    cur ^= 1;
    xp = xp_next;
  }
  if (g < NH) hT[b*NH + g] = h_s[cur][g];
}

// ---------------- K5: head
__global__ __launch_bounds__(256) void k5_head(
    const float* __restrict__ hT, const float* __restrict__ W_head,
    const float* __restrict__ b_head, float* __restrict__ out) {
  const int idx = blockIdx.x*256 + threadIdx.x;
  if (idx >= NB*63) return;
  const int b = idx / 63, r = idx % 63;
  const float* hv = hT + b*NH;
  const float* wr = W_head + r*NH;
  float acc = b_head[r];
#pragma unroll
  for (int k = 0; k < NH; ++k) acc += hv[k]*wr[k];
  out[idx] = acc;
}

extern "C" void kernel_launch(void* const* d_in, const int* in_sizes, int n_in,
                              void* d_out, int out_size, void* d_ws, size_t ws_size,
                              hipStream_t stream) {
  const float* x      = (const float*)d_in[0];
  const float* A      = (const float*)d_in[1];
  const float* W1     = (const float*)d_in[2];
  const float* b1     = (const float*)d_in[3];
  const float* W2     = (const float*)d_in[4];
  const float* b2     = (const float*)d_in[5];
  const float* Wa     = (const float*)d_in[6];
  // d_in[7] = ba : softmax-invariant, unused
  const float* W_ih   = (const float*)d_in[8];
  const float* b_ih   = (const float*)d_in[9];
  const float* W_hh   = (const float*)d_in[10];
  const float* b_hh   = (const float*)d_in[11];
  const float* W_head = (const float*)d_in[12];
  const float* b_head = (const float*)d_in[13];
  float* out = (float*)d_out;

  char* ws = (char*)d_ws;
  size_t off = 0;
  unsigned short* h2 = (unsigned short*)(ws + off); off += (size_t)NB*NT*JH*2;  // 176 MB
  float* scorepart   = (float*)(ws + off);          off += (size_t)NB*16*NJ*4;
  float* attn        = (float*)(ws + off);          off += (size_t)NB*NJ*4;
  off = (off + 15) & ~(size_t)15;
  float* xproj       = (float*)(ws + off);          off += (size_t)NB*NT*G3*4;  // 50 MB
  float* hT          = (float*)(ws + off);          off += (size_t)NB*NH*4;
  off = (off + 15) & ~(size_t)15;
  unsigned short* Wbf = (unsigned short*)(ws + off); off += (size_t)G3*JH*2;    // 516 KB

  k0_convw<<<dim3(252),     256, 0, stream>>>(W_ih, Wbf);
  k1_gcn <<<dim3(NB, 16),   256, 0, stream>>>(x, A, W1, b1, W2, b2, Wa, h2, scorepart);
  k2_attn<<<dim3(NB),        64, 0, stream>>>(scorepart, attn, out + OUT0);
  k3_xproj_mfma<<<dim3(512),256, 0, stream>>>(h2, Wbf, b_ih, attn, xproj);
  k4_gru <<<dim3(NB),       192, 0, stream>>>(xproj, W_hh, b_hh, hT);
  k5_head<<<dim3((NB*63 + 255)/256), 256, 0, stream>>>(hT, W_head, b_head, out);
}

// Round 4
// 555.607 us; speedup vs baseline: 2.1565x; 1.3657x over previous
//
#include <hip/hip_runtime.h>
#include <cstdint>
#include <cstddef>

#define NB 128
#define NT 512
#define NJ 21
#define NC 3
#define NH 64
#define JH 1344   // NJ*NH
#define G3 192    // 3*NH
#define OUT0 (NB*NJ*NC) // 8064
#define FB 4      // frames per k1 block (one per wave)

typedef __attribute__((ext_vector_type(8))) __bf16 bf16x8;
typedef __attribute__((ext_vector_type(4))) float f32x4;

__device__ __forceinline__ float bf2f(unsigned short u) {
  union { unsigned int i; float f; } v; v.i = ((unsigned int)u) << 16; return v.f;
}
__device__ __forceinline__ unsigned short f2bf(float f) {
  union { float f; unsigned int i; } v; v.f = f;
  unsigned int x = v.i;
  unsigned int lsb = (x >> 16) & 1u;
  x += 0x7fffu + lsb;
  return (unsigned short)(x >> 16);
}
__device__ __forceinline__ unsigned int pk_bf16(float lo, float hi) {
  unsigned int r;
  asm("v_cvt_pk_bf16_f32 %0, %1, %2" : "=v"(r) : "v"(lo), "v"(hi));
  return r;
}
__device__ __forceinline__ unsigned int scale2(unsigned int u, float s) {
  float lo = __uint_as_float(u << 16);
  float hi = __uint_as_float(u & 0xffff0000u);
  return pk_bf16(lo * s, hi * s);
}

// ---------------- K0: convert W_ih (192x1344 f32) to bf16
__global__ __launch_bounds__(256) void k0_convw(
    const float* __restrict__ W, unsigned short* __restrict__ Wbf) {
  const int ti = blockIdx.x*256 + threadIdx.x;
  const float4 v = ((const float4*)W)[ti];
  uint2 o;
  o.x = (unsigned int)f2bf(v.x) | ((unsigned int)f2bf(v.y) << 16);
  o.y = (unsigned int)f2bf(v.z) | ((unsigned int)f2bf(v.w) << 16);
  ((uint2*)Wbf)[ti] = o;
}

// ---------------- K1: fused GCN x2 via MFMA, linear padded LDS (no swizzle).
// Wave w owns frame f=w. h1 (VALU) -> h1s[128 rows][72]; GEMM-1 u = h1 @ W2^T
// (MFMA, M=128/K=64/N=64) -> us[4][64][40]; A-agg h2^T = u^T @ A^T (MFMA,
// K=32, adjacency bf16) -> h2st -> coalesced global store. Row pads give
// stride-36/20-dword rows => <=2-way bank aliasing (free).
__global__ __launch_bounds__(256, 2) void k1_fused(
    const float* __restrict__ x, const float* __restrict__ A,
    const float* __restrict__ W1, const float* __restrict__ b1,
    const float* __restrict__ W2, const float* __restrict__ b2,
    const float* __restrict__ Wa,
    unsigned short* __restrict__ h2out, float* __restrict__ scorepart) {
  __shared__ unsigned short h1s[FB*32*72];   // 18 KB  [row][72]
  __shared__ unsigned short us[FB*64*40];    // 20 KB  us[f][h][40]
  __shared__ unsigned short w2s[64*72];      // 9 KB   [h][72]
  __shared__ unsigned short adjs[32*40];     // 2.5 KB [i][40]
  __shared__ unsigned short h2st[FB*NJ*72];  // 11.8 KB [f*21+i][72]
  __shared__ float afs[NJ*NJ];
  __shared__ float xs[4][64];
  __shared__ float ags[4][64];
  __shared__ float spred[4][NJ];

  const int tid = threadIdx.x;
  const int w = tid >> 6, l = tid & 63;
  const int q = l >> 4, r = l & 15;
  const int b = blockIdx.x >> 7, ch = blockIdx.x & 127;
  const int t0 = ch * FB;

  // ---- stage constants
  for (int i = tid; i < NJ*NJ; i += 256) afs[i] = A[i];
  for (int i = tid; i < 1024; i += 256) {
    const int ii = i >> 5, jj = i & 31;
    adjs[ii*40 + jj] = (ii < NJ && jj < NJ) ? f2bf(A[ii*NJ + jj]) : (unsigned short)0;
  }
  {
    const int h = tid & 63, qd = tid >> 6;
    const int g0 = qd * 16;
#pragma unroll
    for (int e = 0; e < 16; e += 2) {
      const float v0 = W2[h*64 + g0 + e], v1 = W2[h*64 + g0 + e + 1];
      ((unsigned int*)w2s)[h*36 + ((g0 + e) >> 1)] = pk_bf16(v0, v1);
    }
  }
  // zero own-frame pad rows j=21..31 (cols 0..63)
#pragma unroll
  for (int j = NJ; j < 32; ++j)
    ((unsigned int*)h1s)[(w*32 + j)*36 + (l & 31)] = 0u;

  const float w1r0 = W1[l*3+0], w1r1 = W1[l*3+1], w1r2 = W1[l*3+2];
  const float b1h = b1[l];
  float b2v[4][4], wav[4][4];
#pragma unroll
  for (int mt = 0; mt < 4; ++mt)
#pragma unroll
    for (int rg = 0; rg < 4; ++rg) {
      const int h = mt*16 + q*4 + rg;
      b2v[mt][rg] = b2[h]; wav[mt][rg] = Wa[h];
    }
  __syncthreads();   // B0: constants ready

  // ---- layer 1 (VALU), frame f = w
  {
    const size_t fr = (size_t)(b*NT + t0 + w);
    if (l < NJ*NC) xs[w][l] = x[fr*(NJ*NC) + l];
    if (l < NJ*NC) {
      const int ji = l / 3, c = l - ji*3;
      float s = 0.f;
#pragma unroll
      for (int j = 0; j < NJ; ++j) s += afs[ji*NJ + j] * xs[w][j*3 + c];
      ags[w][l] = s;
    }
#pragma unroll
    for (int j = 0; j < NJ; ++j) {
      float v = b1h + w1r0*ags[w][j*3+0] + w1r1*ags[w][j*3+1] + w1r2*ags[w][j*3+2];
      v = fmaxf(v, 0.f);
      h1s[(w*32 + j)*72 + l] = f2bf(v);
    }
  }
  __syncthreads();   // B1: h1s ready

  // ---- GEMM-1 (MFMA): u = h1 @ W2^T  (wave m-tiles 2w, 2w+1)
  bf16x8 bw[2][4];
#pragma unroll
  for (int ks = 0; ks < 2; ++ks)
#pragma unroll
    for (int nt = 0; nt < 4; ++nt)
      bw[ks][nt] = *(const bf16x8*)(&w2s[(nt*16 + r)*72 + (ks*4 + q)*8]);
  f32x4 acc1[2][4];
#pragma unroll
  for (int i = 0; i < 2; ++i)
#pragma unroll
    for (int j2 = 0; j2 < 4; ++j2) acc1[i][j2] = (f32x4)0.f;
#pragma unroll
  for (int mti = 0; mti < 2; ++mti) {
    const int row = (w*2 + mti)*16 + r;
#pragma unroll
    for (int ks = 0; ks < 2; ++ks) {
      const bf16x8 af = *(const bf16x8*)(&h1s[row*72 + (ks*4 + q)*8]);
#pragma unroll
      for (int nt = 0; nt < 4; ++nt)
        acc1[mti][nt] = __builtin_amdgcn_mfma_f32_16x16x32_bf16(af, bw[ks][nt], acc1[mti][nt], 0,0,0);
    }
  }
  // write us[f=w][h][j] = u[j][h]  (C/D: col=h is lane r-group, row=j = q*4+reg)
#pragma unroll
  for (int mti = 0; mti < 2; ++mti)
#pragma unroll
    for (int nt = 0; nt < 4; ++nt) {
      const int h = nt*16 + r;
#pragma unroll
      for (int rp = 0; rp < 2; ++rp) {
        const int jp = mti*16 + q*4 + rp*2;
        ((unsigned int*)us)[(w*64 + h)*20 + (jp >> 1)] =
            pk_bf16(acc1[mti][nt][rp*2], acc1[mti][nt][rp*2+1]);
      }
    }
  __syncthreads();   // B2: us ready

  // ---- A-agg (MFMA): D2[h][i] = sum_j u[j][h] * Aadj[i][j]
  bf16x8 badj[2];
#pragma unroll
  for (int nt = 0; nt < 2; ++nt)
    badj[nt] = *(const bf16x8*)(&adjs[(nt*16 + r)*40 + q*8]);
  f32x4 acc2[4][2];
#pragma unroll
  for (int i = 0; i < 4; ++i) { acc2[i][0] = (f32x4)0.f; acc2[i][1] = (f32x4)0.f; }
#pragma unroll
  for (int mt = 0; mt < 4; ++mt) {
    const int h = mt*16 + r;
    const bf16x8 af = *(const bf16x8*)(&us[(w*64 + h)*40 + q*8]);
#pragma unroll
    for (int nt = 0; nt < 2; ++nt)
      acc2[mt][nt] = __builtin_amdgcn_mfma_f32_16x16x32_bf16(af, badj[nt], acc2[mt][nt], 0,0,0);
  }
  // epilogue: relu(+b2), score partials, h2st
  float sp0 = 0.f, sp1 = 0.f;
#pragma unroll
  for (int nt = 0; nt < 2; ++nt) {
    const int i = nt*16 + r;
    if (i < NJ) {
#pragma unroll
      for (int mt = 0; mt < 4; ++mt)
#pragma unroll
        for (int rp = 0; rp < 2; ++rp) {
          const int h0 = mt*16 + q*4 + rp*2;
          const float v0 = fmaxf(acc2[mt][nt][rp*2]   + b2v[mt][rp*2],   0.f);
          const float v1 = fmaxf(acc2[mt][nt][rp*2+1] + b2v[mt][rp*2+1], 0.f);
          if (nt == 0) sp0 += v0*wav[mt][rp*2] + v1*wav[mt][rp*2+1];
          else         sp1 += v0*wav[mt][rp*2] + v1*wav[mt][rp*2+1];
          ((unsigned int*)h2st)[(w*NJ + i)*36 + (h0 >> 1)] = pk_bf16(v0, v1);
        }
    }
  }
  // score reduction across q-groups (lanes l, l^16, l^32, l^48)
  sp0 += __shfl_xor(sp0, 16); sp0 += __shfl_xor(sp0, 32);
  sp1 += __shfl_xor(sp1, 16); sp1 += __shfl_xor(sp1, 32);
  if (l < 16) spred[w][l] = sp0;
  if (l < 5)  spred[w][16 + l] = sp1;
  __syncthreads();   // B3: h2st + spred ready

  if (tid < NJ)
    scorepart[((size_t)b*128 + ch)*NJ + tid] =
      spred[0][tid] + spred[1][tid] + spred[2][tid] + spred[3][tid];

  // h2 -> global, coalesced b128
  const size_t gbase = (size_t)(b*NT + t0) * JH;
  for (int cid = tid; cid < FB*NJ*8; cid += 256) {
    const int f = cid / (NJ*8), rem = cid - f*(NJ*8);
    const int i = rem >> 3, p = rem & 7;
    const uint4 v = *(const uint4*)(&h2st[(f*NJ + i)*72 + p*8]);
    *(uint4*)(&h2out[gbase + (size_t)f*JH + i*64 + p*8]) = v;
  }
}

// ---------------- K2: reduce score partials, softmax over joints
__global__ __launch_bounds__(64) void k2_attn(
    const float* __restrict__ scorepart, float* __restrict__ attn,
    float* __restrict__ out_attn) {
  __shared__ float ss[NJ];
  const int b = blockIdx.x, tid = threadIdx.x;
  if (tid < NJ) {
    float s = 0.f;
    for (int ch = 0; ch < 128; ++ch) s += scorepart[(b*128 + ch)*NJ + tid];
    ss[tid] = s * (1.0f/NT);
  }
  __syncthreads();
  float m = -1e30f;
  for (int j = 0; j < NJ; ++j) m = fmaxf(m, ss[j]);
  float sum = 0.f;
  for (int j = 0; j < NJ; ++j) sum += expf(ss[j] - m);
  if (tid < NJ) {
    float a = expf(ss[tid] - m) / sum;
    attn[b*NJ + tid] = a;
    out_attn[b*NJ + tid] = a;
  }
}

// ---------------- K3: xproj = (h2 * attn) @ W_ih.T + b_ih  -- MFMA bf16
__global__ __launch_bounds__(256, 2) void k3_xproj_mfma(
    const unsigned short* __restrict__ h2, const unsigned short* __restrict__ Wbf,
    const float* __restrict__ b_ih, const float* __restrict__ attn,
    float* __restrict__ xproj) {
  __shared__ unsigned short Abuf[2][128*32];
  __shared__ unsigned short Bbuf[2][192*32];
  const int tid = threadIdx.x;
  const int w = tid >> 6, l = tid & 63;
  const int lq = l >> 4, lr = l & 15;
  const int blk = blockIdx.x;
  const int b = blk >> 2;
  const int t0 = (blk & 3) << 7;
  const int wm = w >> 1, wn = w & 1;

  const unsigned short* gA[2]; int ldsA[2];
#pragma unroll
  for (int i = 0; i < 2; ++i) {
    const int lc = tid*2 + i, rr = lc >> 2, j = lc & 3;
    gA[i] = h2 + (size_t)(b*NT + t0 + rr)*JH + j*8;
    ldsA[i] = rr*32 + ((j ^ ((rr>>1)&3)) << 3);
  }
  const unsigned short* gB[3]; int ldsB[3];
#pragma unroll
  for (int i = 0; i < 3; ++i) {
    const int lc = tid + 256*i, g = lc >> 2, j = lc & 3;
    gB[i] = Wbf + (size_t)g*JH + j*8;
    ldsB[i] = g*32 + ((j ^ ((g>>1)&3)) << 3);
  }
  int aoff[4], boff[6];
#pragma unroll
  for (int mt = 0; mt < 4; ++mt) {
    const int row = wm*64 + mt*16 + lr;
    aoff[mt] = row*32 + ((lq ^ ((row>>1)&3)) << 3);
  }
#pragma unroll
  for (int nt = 0; nt < 6; ++nt) {
    const int g = wn*96 + nt*16 + lr;
    boff[nt] = g*32 + ((lq ^ ((g>>1)&3)) << 3);
  }

  f32x4 acc[4][6];
#pragma unroll
  for (int mt = 0; mt < 4; ++mt)
#pragma unroll
    for (int nt = 0; nt < 6; ++nt) acc[mt][nt] = (f32x4)0.f;

  {
    const float s = attn[b*NJ + 0];
#pragma unroll
    for (int i = 0; i < 2; ++i)
      *(uint4*)(&Abuf[0][ldsA[i]]) = *(const uint4*)(gA[i]);
#pragma unroll
    for (int i = 0; i < 3; ++i) {
      uint4 v = *(const uint4*)(gB[i]);
      v.x = scale2(v.x, s); v.y = scale2(v.y, s);
      v.z = scale2(v.z, s); v.w = scale2(v.w, s);
      *(uint4*)(&Bbuf[0][ldsB[i]]) = v;
    }
  }
  __syncthreads();

  for (int ks = 0; ks < 42; ++ks) {
    const int cur = ks & 1;
    uint4 av0, av1, bv0, bv1, bv2;
    if (ks < 41) {
      const int kk = (ks+1)*32;
      av0 = *(const uint4*)(gA[0] + kk);
      av1 = *(const uint4*)(gA[1] + kk);
      bv0 = *(const uint4*)(gB[0] + kk);
      bv1 = *(const uint4*)(gB[1] + kk);
      bv2 = *(const uint4*)(gB[2] + kk);
    }
    bf16x8 af[4], bfr[6];
#pragma unroll
    for (int mt = 0; mt < 4; ++mt) af[mt] = *(const bf16x8*)(&Abuf[cur][aoff[mt]]);
#pragma unroll
    for (int nt = 0; nt < 6; ++nt) bfr[nt] = *(const bf16x8*)(&Bbuf[cur][boff[nt]]);
#pragma unroll
    for (int mt = 0; mt < 4; ++mt)
#pragma unroll
      for (int nt = 0; nt < 6; ++nt)
        acc[mt][nt] = __builtin_amdgcn_mfma_f32_16x16x32_bf16(af[mt], bfr[nt], acc[mt][nt], 0, 0, 0);
    if (ks < 41) {
      const float s = attn[b*NJ + ((ks+1) >> 1)];
      *(uint4*)(&Abuf[cur^1][ldsA[0]]) = av0;
      *(uint4*)(&Abuf[cur^1][ldsA[1]]) = av1;
      uint4 v;
      v = bv0; v.x = scale2(v.x, s); v.y = scale2(v.y, s); v.z = scale2(v.z, s); v.w = scale2(v.w, s);
      *(uint4*)(&Bbuf[cur^1][ldsB[0]]) = v;
      v = bv1; v.x = scale2(v.x, s); v.y = scale2(v.y, s); v.z = scale2(v.z, s); v.w = scale2(v.w, s);
      *(uint4*)(&Bbuf[cur^1][ldsB[1]]) = v;
      v = bv2; v.x = scale2(v.x, s); v.y = scale2(v.y, s); v.z = scale2(v.z, s); v.w = scale2(v.w, s);
      *(uint4*)(&Bbuf[cur^1][ldsB[2]]) = v;
    }
    __syncthreads();
  }

  float bias[6];
#pragma unroll
  for (int nt = 0; nt < 6; ++nt) bias[nt] = b_ih[wn*96 + nt*16 + lr];
#pragma unroll
  for (int mt = 0; mt < 4; ++mt)
#pragma unroll
    for (int nt = 0; nt < 6; ++nt) {
      const int g = wn*96 + nt*16 + lr;
#pragma unroll
      for (int rr = 0; rr < 4; ++rr) {
        const int trow = t0 + wm*64 + mt*16 + lq*4 + rr;
        xproj[(size_t)(b*NT + trow)*G3 + g] = acc[mt][nt][rr] + bias[nt];
      }
    }
}

// ---------------- K4: GRU over time, one block per batch
__global__ __launch_bounds__(192) void k4_gru(
    const float* __restrict__ xproj, const float* __restrict__ W_hh,
    const float* __restrict__ b_hh, float* __restrict__ hT) {
  __shared__ float h_s[2][NH];
  __shared__ float rz_s[2*NH];
  __shared__ float xn_s[NH];
  __shared__ float hn_s[NH];
  const int b = blockIdx.x, g = threadIdx.x;
  float wh[NH];
  {
    const float4* p = (const float4*)(W_hh + g*NH);
#pragma unroll
    for (int qq = 0; qq < 16; ++qq) {
      float4 v = p[qq];
      wh[4*qq+0]=v.x; wh[4*qq+1]=v.y; wh[4*qq+2]=v.z; wh[4*qq+3]=v.w;
    }
  }
  const float bh = b_hh[g];
  if (g < NH) h_s[0][g] = 0.f;
  __syncthreads();
  int cur = 0;
  const float* xp_base = xproj + (size_t)b*NT*G3;
  float xp = xp_base[g];
  for (int t = 0; t < NT; ++t) {
    float xp_next = (t+1 < NT) ? xp_base[(size_t)(t+1)*G3 + g] : 0.f;
    float a0=0.f, a1=0.f, a2=0.f, a3=0.f;
    const float4* h4 = (const float4*)(h_s[cur]);
#pragma unroll
    for (int qq = 0; qq < 16; qq += 4) {
      float4 v0 = h4[qq+0], v1 = h4[qq+1], v2 = h4[qq+2], v3 = h4[qq+3];
      a0 += v0.x*wh[4*qq+0]  + v0.y*wh[4*qq+1]  + v0.z*wh[4*qq+2]  + v0.w*wh[4*qq+3];
      a1 += v1.x*wh[4*qq+4]  + v1.y*wh[4*qq+5]  + v1.z*wh[4*qq+6]  + v1.w*wh[4*qq+7];
      a2 += v2.x*wh[4*qq+8]  + v2.y*wh[4*qq+9]  + v2.z*wh[4*qq+10] + v2.w*wh[4*qq+11];
      a3 += v3.x*wh[4*qq+12] + v3.y*wh[4*qq+13] + v3.z*wh[4*qq+14] + v3.w*wh[4*qq+15];
    }
    const float gh = bh + ((a0 + a1) + (a2 + a3));
    if (g < 2*NH) { rz_s[g] = xp + gh; }
    else          { xn_s[g-2*NH] = xp; hn_s[g-2*NH] = gh; }
    __syncthreads();
    if (g < NH) {
      const float r = 1.f/(1.f + expf(-rz_s[g]));
      const float z = 1.f/(1.f + expf(-rz_s[NH+g]));
      const float n = tanhf(xn_s[g] + r*hn_s[g]);
      h_s[cur^1][g] = (1.f - z)*n + z*h_s[cur][g];
    }
    __syncthreads();
    cur ^= 1;
    xp = xp_next;
  }
  if (g < NH) hT[b*NH + g] = h_s[cur][g];
}

// ---------------- K5: head
__global__ __launch_bounds__(256) void k5_head(
    const float* __restrict__ hT, const float* __restrict__ W_head,
    const float* __restrict__ b_head, float* __restrict__ out) {
  const int idx = blockIdx.x*256 + threadIdx.x;
  if (idx >= NB*63) return;
  const int b = idx / 63, rr = idx % 63;
  const float* hv = hT + b*NH;
  const float* wr = W_head + rr*NH;
  float acc = b_head[rr];
#pragma unroll
  for (int k = 0; k < NH; ++k) acc += hv[k]*wr[k];
  out[idx] = acc;
}

extern "C" void kernel_launch(void* const* d_in, const int* in_sizes, int n_in,
                              void* d_out, int out_size, void* d_ws, size_t ws_size,
                              hipStream_t stream) {
  const float* x      = (const float*)d_in[0];
  const float* A      = (const float*)d_in[1];
  const float* W1     = (const float*)d_in[2];
  const float* b1     = (const float*)d_in[3];
  const float* W2     = (const float*)d_in[4];
  const float* b2     = (const float*)d_in[5];
  const float* Wa     = (const float*)d_in[6];
  // d_in[7] = ba : softmax-invariant, unused
  const float* W_ih   = (const float*)d_in[8];
  const float* b_ih   = (const float*)d_in[9];
  const float* W_hh   = (const float*)d_in[10];
  const float* b_hh   = (const float*)d_in[11];
  const float* W_head = (const float*)d_in[12];
  const float* b_head = (const float*)d_in[13];
  float* out = (float*)d_out;

  char* ws = (char*)d_ws;
  size_t off = 0;
  unsigned short* h2 = (unsigned short*)(ws + off); off += (size_t)NB*NT*JH*2;   // 176 MB
  float* scorepart   = (float*)(ws + off);          off += (size_t)NB*128*NJ*4;  // 1.38 MB
  float* attn        = (float*)(ws + off);          off += (size_t)NB*NJ*4;
  off = (off + 15) & ~(size_t)15;
  float* xproj       = (float*)(ws + off);          off += (size_t)NB*NT*G3*4;   // 50 MB
  float* hT          = (float*)(ws + off);          off += (size_t)NB*NH*4;
  off = (off + 15) & ~(size_t)15;
  unsigned short* Wbf = (unsigned short*)(ws + off); off += (size_t)G3*JH*2;     // 516 KB

  k0_convw<<<dim3(252),       256, 0, stream>>>(W_ih, Wbf);
  k1_fused<<<dim3(NB*128),    256, 0, stream>>>(x, A, W1, b1, W2, b2, Wa, h2, scorepart);
  k2_attn<<<dim3(NB),          64, 0, stream>>>(scorepart, attn, out + OUT0);
  k3_xproj_mfma<<<dim3(512),  256, 0, stream>>>(h2, Wbf, b_ih, attn, xproj);
  k4_gru <<<dim3(NB),         192, 0, stream>>>(xproj, W_hh, b_hh, hT);
  k5_head<<<dim3((NB*63 + 255)/256), 256, 0, stream>>>(hT, W_head, b_head, out);
}